// Round 8
// baseline (398.504 us; speedup 1.0000x reference)
//
#include <hip/hip_runtime.h>
#include <math.h>

#define EMB_D 64
#define N_EMB_K 1024
#define HW 4096        // 64*64
#define CHW 262144     // 64*4096
#define NPTS 65536     // 16*64*64
#define Q_OFF 1
#define PERP_OFF 4194305
#define ENC_OFF 4194306
#define FRAG_OFF 4096    // floats: W fragments at ws+16KB
#define IDX_OFF 69632    // ints: idx[65536] at ws+272KB

// ws layout (floats): [0..1023] c[k]=0.5||W_k||^2 ; [1024..2047] hist(uint) ;
// [2048] loss ; [4096..69631] hi/lo bf16 B-frags (256 KB) ; [69632..135167] idx

typedef __attribute__((ext_vector_type(8))) short short8;   // MFMA A/B frag
typedef __attribute__((ext_vector_type(4))) float float4v;  // MFMA C/D frag
typedef __attribute__((ext_vector_type(2))) float f2;
typedef __attribute__((ext_vector_type(4))) float f4;

union S8 { short8 v; unsigned short u[8]; };

__device__ __forceinline__ unsigned short f2bf_rne(float f) {
    unsigned u = __builtin_bit_cast(unsigned, f);
    unsigned r = u + 0x7FFFu + ((u >> 16) & 1u);
    return (unsigned short)(r >> 16);
}
__device__ __forceinline__ float bf2f(unsigned short h) {
    unsigned u = ((unsigned)h) << 16;
    return __builtin_bit_cast(float, u);
}

__global__ __launch_bounds__(256) void vq_prep(const float* __restrict__ W,
                                               float* __restrict__ ws) {
    const int gid = blockIdx.x * 256 + threadIdx.x;   // 0..8191
    {
        const int code = gid >> 3;
        const int seg  = gid & 7;
        const int d0   = seg << 3;
        const int t    = code >> 4;
        const int n    = code & 15;
        const int ks   = seg >> 2;
        const int lane = ((seg & 3) << 4) + n;
        const float4* wp = (const float4*)(W + (code << 6) + d0);
        const float4 g0 = wp[0], g1 = wp[1];
        const float vv[8] = {g0.x, g0.y, g0.z, g0.w, g1.x, g1.y, g1.z, g1.w};
        S8 hs, ls;
        #pragma unroll
        for (int j = 0; j < 8; ++j) {
            hs.u[j] = f2bf_rne(vv[j]);
            ls.u[j] = f2bf_rne(vv[j] - bf2f(hs.u[j]));
        }
        short8* frag = (short8*)(ws + FRAG_OFF);
        frag[(t * 4 + ks * 2 + 0) * 64 + lane] = hs.v;
        frag[(t * 4 + ks * 2 + 1) * 64 + lane] = ls.v;
    }
    if (gid < N_EMB_K) {
        const float* wk = W + (gid << 6);
        float s = 0.f;
        #pragma unroll
        for (int d = 0; d < EMB_D; ++d) s = fmaf(wk[d], wk[d], s);
        ws[gid] = 0.5f * s;
        ((unsigned int*)ws)[1024 + gid] = 0u;
        if (gid == 0) ws[2048] = 0.f;
    }
}

// 512 blocks x 256 thr; block owns 128 points; wave owns 32 points (2 A-tiles).
// NO enc writes here — idx goes to ws.
__global__ __launch_bounds__(256, 2) void vq_argmin(const float* __restrict__ in,
                                                    const float* __restrict__ W,
                                                    float* __restrict__ out,
                                                    float* __restrict__ ws) {
    __shared__ float x_lds[64 * 128];   // [d][p], 32 KB
    __shared__ int   s_bk[128];

    const int tid  = threadIdx.x;
    const int lane = tid & 63;
    const int wv   = tid >> 6;
    const int n16  = lane & 15;
    const int quad = lane >> 4;

    const int blk = blockIdx.x;
    const int b   = blk >> 5;              // image (32 blocks per image)
    const int hw0 = (blk & 31) * 128;      // 128 consecutive hw positions

    {
        const float* src = in + (size_t)b * CHW + hw0;
        #pragma unroll
        for (int i = 0; i < 32; ++i) {
            const int idx = i * 256 + tid;
            const int d = idx >> 7, p = idx & 127;
            x_lds[idx] = src[d * HW + p];
        }
    }
    __syncthreads();

    // A frags (hi/lo), two 16-pt tiles per wave: m=lane&15, k=quad*8+j
    short8 a0h0, a0l0, a0h1, a0l1, a1h0, a1l0, a1h1, a1l1;
    {
        const int p0 = wv * 32 + n16;
        const int p1 = p0 + 16;
        S8 t0h0, t0l0, t0h1, t0l1, t1h0, t1l0, t1h1, t1l1;
        #pragma unroll
        for (int j = 0; j < 8; ++j) {
            const int d = quad * 8 + j;
            const float v00 = x_lds[d * 128 + p0];
            const float v01 = x_lds[(d + 32) * 128 + p0];
            const float v10 = x_lds[d * 128 + p1];
            const float v11 = x_lds[(d + 32) * 128 + p1];
            t0h0.u[j] = f2bf_rne(v00); t0l0.u[j] = f2bf_rne(v00 - bf2f(t0h0.u[j]));
            t0h1.u[j] = f2bf_rne(v01); t0l1.u[j] = f2bf_rne(v01 - bf2f(t0h1.u[j]));
            t1h0.u[j] = f2bf_rne(v10); t1l0.u[j] = f2bf_rne(v10 - bf2f(t1h0.u[j]));
            t1h1.u[j] = f2bf_rne(v11); t1l1.u[j] = f2bf_rne(v11 - bf2f(t1h1.u[j]));
        }
        a0h0 = t0h0.v; a0l0 = t0l0.v; a0h1 = t0h1.v; a0l1 = t0l1.v;
        a1h0 = t1h0.v; a1l0 = t1l0.v; a1h1 = t1h1.v; a1l1 = t1l1.v;
    }

    float bv0[4] = {-3.0e38f, -3.0e38f, -3.0e38f, -3.0e38f};
    float bv1[4] = {-3.0e38f, -3.0e38f, -3.0e38f, -3.0e38f};
    int   bk0[4] = {0, 0, 0, 0};
    int   bk1[4] = {0, 0, 0, 0};
    const float*  cvec = ws;
    const short8* frag = (const short8*)(ws + FRAG_OFF);

    #pragma unroll 2
    for (int t = 0; t < 64; ++t) {
        const int cb = (t << 2) * 64 + lane;
        const short8 bh0 = frag[cb];
        const short8 bl0 = frag[cb + 64];
        const short8 bh1 = frag[cb + 128];
        const short8 bl1 = frag[cb + 192];
        const float  cv  = cvec[(t << 4) + n16];
        float4v acc0 = {-cv, -cv, -cv, -cv};   // score = x.w - 0.5||w||^2
        float4v acc1 = {-cv, -cv, -cv, -cv};
        acc0 = __builtin_amdgcn_mfma_f32_16x16x32_bf16(a0h0, bh0, acc0, 0, 0, 0);
        acc1 = __builtin_amdgcn_mfma_f32_16x16x32_bf16(a1h0, bh0, acc1, 0, 0, 0);
        acc0 = __builtin_amdgcn_mfma_f32_16x16x32_bf16(a0h1, bh1, acc0, 0, 0, 0);
        acc1 = __builtin_amdgcn_mfma_f32_16x16x32_bf16(a1h1, bh1, acc1, 0, 0, 0);
        acc0 = __builtin_amdgcn_mfma_f32_16x16x32_bf16(a0l0, bh0, acc0, 0, 0, 0);
        acc1 = __builtin_amdgcn_mfma_f32_16x16x32_bf16(a1l0, bh0, acc1, 0, 0, 0);
        acc0 = __builtin_amdgcn_mfma_f32_16x16x32_bf16(a0l1, bh1, acc0, 0, 0, 0);
        acc1 = __builtin_amdgcn_mfma_f32_16x16x32_bf16(a1l1, bh1, acc1, 0, 0, 0);
        acc0 = __builtin_amdgcn_mfma_f32_16x16x32_bf16(a0h0, bl0, acc0, 0, 0, 0);
        acc1 = __builtin_amdgcn_mfma_f32_16x16x32_bf16(a1h0, bl0, acc1, 0, 0, 0);
        acc0 = __builtin_amdgcn_mfma_f32_16x16x32_bf16(a0h1, bl1, acc0, 0, 0, 0);
        acc1 = __builtin_amdgcn_mfma_f32_16x16x32_bf16(a1h1, bl1, acc1, 0, 0, 0);
        const int code = (t << 4) + n16;
        #pragma unroll
        for (int r = 0; r < 4; ++r) {
            if (acc0[r] > bv0[r]) { bv0[r] = acc0[r]; bk0[r] = code; }  // strict > => lowest k
            if (acc1[r] > bv1[r]) { bv1[r] = acc1[r]; bk1[r] = code; }
        }
    }

    #pragma unroll
    for (int off = 1; off < 16; off <<= 1) {
        #pragma unroll
        for (int r = 0; r < 4; ++r) {
            float ov = __shfl_xor(bv0[r], off, 64);
            int   oi = __shfl_xor(bk0[r], off, 64);
            if (ov > bv0[r] || (ov == bv0[r] && oi < bk0[r])) { bv0[r] = ov; bk0[r] = oi; }
            ov = __shfl_xor(bv1[r], off, 64);
            oi = __shfl_xor(bk1[r], off, 64);
            if (ov > bv1[r] || (ov == bv1[r] && oi < bk1[r])) { bv1[r] = ov; bk1[r] = oi; }
        }
    }
    if (n16 == 0) {
        #pragma unroll
        for (int r = 0; r < 4; ++r) {
            s_bk[wv * 32 + quad * 4 + r]      = bk0[r];
            s_bk[wv * 32 + 16 + quad * 4 + r] = bk1[r];
        }
    }
    __syncthreads();

    if (tid < 128) {
        const int bk = s_bk[tid];
        atomicAdd((unsigned int*)ws + 1024 + bk, 1u);
        ((int*)ws)[IDX_OFF + blk * 128 + tid] = bk;
    }

    // quantized_st (NCHW) + exact fp32 loss
    {
        float* quant = out + Q_OFF;
        const int p    = tid & 127;
        const int half = tid >> 7;
        const int bk = s_bk[p];
        const float* wrow = W + (bk << 6);
        float lsum = 0.f;
        #pragma unroll
        for (int dd = 0; dd < 32; ++dd) {
            const int d = half * 32 + dd;
            const float xv  = x_lds[d * 128 + p];
            const float qv  = wrow[d];
            const float diff = qv - xv;
            lsum = fmaf(diff, diff, lsum);
            quant[(size_t)b * CHW + d * HW + hw0 + p] = xv + diff;
        }
        #pragma unroll
        for (int off = 1; off < 64; off <<= 1) lsum += __shfl_xor(lsum, off, 64);
        if (lane == 0) atomicAdd(ws + 2048, lsum);
    }
}

// fill-mimicking one-hot writer: 4096 blocks x 256 thr; each wave owns 4 whole
// rows (4 KB each); wave-uniform idx; 4 aligned f4 plain stores per lane per row.
__global__ __launch_bounds__(256) void vq_enc(float* __restrict__ out,
                                              const int* __restrict__ idx) {
    const int tid  = threadIdx.x;
    const int lane = tid & 63;
    const int wv   = tid >> 6;
    const int wrow0 = (blockIdx.x * 4 + wv) * 4;   // first of this wave's 4 rows

    float* encbase = out + ENC_OFF;   // byte ≡ 8 mod 16; +2 floats → 16B aligned
    #pragma unroll
    for (int rr = 0; rr < 4; ++rr) {
        const int row = wrow0 + rr;
        const int bk  = idx[row];                 // wave-uniform -> scalar broadcast
        float* rp = encbase + ((size_t)row << 10);
        // interior: 1020 floats = 255 f4 at rp+2+4*j ; lane l covers j = 4l..4l+3 (l<63)
        #pragma unroll
        for (int s = 0; s < 4; ++s) {
            const int j = 4 * lane + s;           // 0..255
            if (j < 255) {
                const int c = 2 + 4 * j;
                f4 v;
                v.x = (bk == c)     ? 1.0f : 0.0f;
                v.y = (bk == c + 1) ? 1.0f : 0.0f;
                v.z = (bk == c + 2) ? 1.0f : 0.0f;
                v.w = (bk == c + 3) ? 1.0f : 0.0f;
                *(f4*)(rp + c) = v;
            }
        }
        if (lane == 63) {
            f2 v0, v1;
            v0.x = (bk == 0)    ? 1.0f : 0.0f;
            v0.y = (bk == 1)    ? 1.0f : 0.0f;
            v1.x = (bk == 1022) ? 1.0f : 0.0f;
            v1.y = (bk == 1023) ? 1.0f : 0.0f;
            *(f2*)(rp)        = v0;
            *(f2*)(rp + 1022) = v1;
        }
    }
}

__global__ __launch_bounds__(256) void vq_final(const float* __restrict__ ws,
                                                float* __restrict__ out) {
    __shared__ float red[256];
    const int tid = threadIdx.x;
    const unsigned int* hist = (const unsigned int*)ws + 1024;
    float local = 0.f;
    #pragma unroll
    for (int j = 0; j < 4; ++j) {
        const unsigned int cnt = hist[tid + j * 256];
        const float pr = (float)cnt * (1.0f / 65536.0f);
        local += pr * logf(pr + 1e-10f);
    }
    red[tid] = local;
    __syncthreads();
    for (int off = 128; off > 0; off >>= 1) {
        if (tid < off) red[tid] += red[tid + off];
        __syncthreads();
    }
    if (tid == 0) {
        out[PERP_OFF] = expf(-red[0]);
        out[0] = 1.25f * ws[2048] * (1.0f / 4194304.0f);
    }
}

extern "C" void kernel_launch(void* const* d_in, const int* in_sizes, int n_in,
                              void* d_out, int out_size, void* d_ws, size_t ws_size,
                              hipStream_t stream) {
    const float* in = (const float*)d_in[0];   // (16,64,64,64) fp32 NCHW
    const float* W  = (const float*)d_in[1];   // (1024,64) fp32
    float* out = (float*)d_out;                // [loss | quant(4194304) | perp | enc(67108864)]
    float* ws  = (float*)d_ws;

    vq_prep<<<32, 256, 0, stream>>>(W, ws);
    vq_argmin<<<NPTS / 128, 256, 0, stream>>>(in, W, out, ws);
    vq_enc<<<NPTS / 16, 256, 0, stream>>>(out, (const int*)ws + IDX_OFF);
    vq_final<<<1, 256, 0, stream>>>(ws, out);
}

// Round 9
// 339.941 us; speedup vs baseline: 1.1723x; 1.1723x over previous
//
#include <hip/hip_runtime.h>
#include <math.h>

#define EMB_D 64
#define N_EMB_K 1024
#define HW 4096        // 64*64
#define CHW 262144     // 64*4096
#define NPTS 65536     // 16*64*64
#define Q_OFF 1
#define PERP_OFF 4194305
#define ENC_OFF 4194306
#define FRAG_OFF 4096   // floats: bf16-hi W fragments at ws+16KB (128 KB)

// ws layout (floats): [0..1023] c[k]=0.5||W_k||^2 ; [1024..2047] hist(uint) ;
// [2048] loss ; [4096..36863] bf16-hi B-frags (128 KB, chunk-lane order)

typedef __attribute__((ext_vector_type(8))) short short8;   // MFMA A/B frag (4 VGPRs)
typedef __attribute__((ext_vector_type(4))) float float4v;  // MFMA C/D frag
typedef __attribute__((ext_vector_type(2))) float f2;
typedef __attribute__((ext_vector_type(4))) float f4;

union S8 { short8 v; unsigned short u[8]; };

__device__ __forceinline__ unsigned short f2bf_rne(float f) {
    unsigned u = __builtin_bit_cast(unsigned, f);
    unsigned r = u + 0x7FFFu + ((u >> 16) & 1u);
    return (unsigned short)(r >> 16);
}
__device__ __forceinline__ float bf2f(unsigned short h) {
    unsigned u = ((unsigned)h) << 16;
    return __builtin_bit_cast(float, u);
}

// 32 blocks x 256: c[k], hist/loss zero, bf16-hi frags.
// chunk = (code>>4)*2 + ks, lane = kg*16 + (code&15); element j <-> d = ks*32+kg*8+j
__global__ __launch_bounds__(256) void vq_prep(const float* __restrict__ W,
                                               float* __restrict__ ws) {
    const int gid = blockIdx.x * 256 + threadIdx.x;   // 0..8191
    {
        const int code = gid >> 3;
        const int seg  = gid & 7;           // ks = seg>>2, kg = seg&3
        const int d0   = seg << 3;
        const float4* wp = (const float4*)(W + (code << 6) + d0);
        const float4 g0 = wp[0], g1 = wp[1];
        const float vv[8] = {g0.x, g0.y, g0.z, g0.w, g1.x, g1.y, g1.z, g1.w};
        S8 hs;
        #pragma unroll
        for (int j = 0; j < 8; ++j) hs.u[j] = f2bf_rne(vv[j]);
        const int chunk = (code >> 4) * 2 + (seg >> 2);
        const int lane  = ((seg & 3) << 4) + (code & 15);
        ((short8*)(ws + FRAG_OFF))[chunk * 64 + lane] = hs.v;
    }
    if (gid < N_EMB_K) {
        const float* wk = W + (gid << 6);
        float s = 0.f;
        #pragma unroll
        for (int d = 0; d < EMB_D; ++d) s = fmaf(wk[d], wk[d], s);
        ws[gid] = 0.5f * s;
        ((unsigned int*)ws)[1024 + gid] = 0u;
        if (gid == 0) ws[2048] = 0.f;
    }
}

// 1024 blocks x 256 thr, 1 block/CU (135 KB LDS). Block owns 64 points.
// k-loop: LDS-only loads (lgkmcnt) + MFMA + interleaved enc-zero stores (vmcnt,
// unwaited until the single end barrier) -> stores drain under compute.
__global__ __launch_bounds__(256, 1) void vq_main(const float* __restrict__ in,
                                                  const float* __restrict__ W,
                                                  float* __restrict__ out,
                                                  float* __restrict__ ws) {
    __shared__ short8 frag_lds[8192];   // 128 KB: [chunk*64 + lane]
    __shared__ float  c_lds[1024];      // 4 KB
    __shared__ int    s_bk[64];

    const int tid  = threadIdx.x;
    const int lane = tid & 63;
    const int wv   = tid >> 6;
    const int n16  = lane & 15;
    const int quad = lane >> 4;

    const int blk = blockIdx.x;
    const int b   = blk >> 6;              // image (64 blocks per image)
    const int hw0 = (blk & 63) * 64;       // 64 consecutive hw positions

    // ---- stage frags + c into LDS (plain loads; no stores in flight yet) ----
    {
        const short8* fsrc = (const short8*)(ws + FRAG_OFF);
        #pragma unroll
        for (int i = 0; i < 32; ++i) frag_lds[i * 256 + tid] = fsrc[i * 256 + tid];
        ((f4*)c_lds)[tid] = ((const f4*)ws)[tid];
    }

    // ---- x in registers + A-frags (x hi/lo): point p = wv*16+n16, d = quad*8+j (+32) ----
    float qx[16];
    short8 ah0, ah1, al0, al1;
    {
        const float* xp = in + (size_t)b * CHW + hw0 + (wv * 16 + n16);
        S8 h0, h1, l0, l1;
        #pragma unroll
        for (int j = 0; j < 8; ++j) {
            const int d = quad * 8 + j;
            const float v0 = xp[d * HW];
            const float v1 = xp[(d + 32) * HW];
            qx[j]     = v0;
            qx[j + 8] = v1;
            h0.u[j] = f2bf_rne(v0); l0.u[j] = f2bf_rne(v0 - bf2f(h0.u[j]));
            h1.u[j] = f2bf_rne(v1); l1.u[j] = f2bf_rne(v1 - bf2f(h1.u[j]));
        }
        ah0 = h0.v; al0 = l0.v; ah1 = h1.v; al1 = l1.v;
    }
    __syncthreads();   // frags/c visible; all x loads consumed before any store

    float bestv[4] = {-3.0e38f, -3.0e38f, -3.0e38f, -3.0e38f};
    int   bestk[4] = {0, 0, 0, 0};
    float* encrow0 = out + ENC_OFF + (size_t)blk * 65536;   // block's 64 rows
    const f4 z4 = {0.f, 0.f, 0.f, 0.f};
    const f2 z2 = {0.f, 0.f};

    // ---- k-loop: 64 tiles; per tile 2 ds_read_b128 + 1 ds_read + 4 MFMA
    //      + one enc-zero store (tile t <-> row t), never waited inside loop ----
    #pragma unroll 2
    for (int t = 0; t < 64; ++t) {
        const short8 bh0 = frag_lds[(2 * t) * 64 + lane];
        const short8 bh1 = frag_lds[(2 * t + 1) * 64 + lane];
        const float  cv  = c_lds[(t << 4) + n16];
        {   // zero row t: interior 255 f4 (16B-aligned at +2 floats) + edges
            float* row = encrow0 + t * 1024;
            if (tid < 255) {
                *(f4*)(row + 2 + 4 * tid) = z4;
            } else {
                *(f2*)(row)        = z2;
                *(f2*)(row + 1022) = z2;
            }
        }
        float4v acc = {-cv, -cv, -cv, -cv};   // score = x.w - 0.5||w||^2
        acc = __builtin_amdgcn_mfma_f32_16x16x32_bf16(ah0, bh0, acc, 0, 0, 0);
        acc = __builtin_amdgcn_mfma_f32_16x16x32_bf16(ah1, bh1, acc, 0, 0, 0);
        acc = __builtin_amdgcn_mfma_f32_16x16x32_bf16(al0, bh0, acc, 0, 0, 0);
        acc = __builtin_amdgcn_mfma_f32_16x16x32_bf16(al1, bh1, acc, 0, 0, 0);
        const int code = (t << 4) + n16;
        #pragma unroll
        for (int r = 0; r < 4; ++r) {
            if (acc[r] > bestv[r]) { bestv[r] = acc[r]; bestk[r] = code; }  // strict > => lowest k
        }
    }

    // ---- reduce across the 16 code-lanes of each row group ----
    #pragma unroll
    for (int off = 1; off < 16; off <<= 1) {
        #pragma unroll
        for (int r = 0; r < 4; ++r) {
            const float ov = __shfl_xor(bestv[r], off, 64);
            const int   oi = __shfl_xor(bestk[r], off, 64);
            if (ov > bestv[r] || (ov == bestv[r] && oi < bestk[r])) {
                bestv[r] = ov; bestk[r] = oi;
            }
        }
    }
    if (n16 == 0) {
        #pragma unroll
        for (int r = 0; r < 4; ++r) s_bk[wv * 16 + quad * 4 + r] = bestk[r];
    }
    __syncthreads();   // publishes s_bk AND drains the (mostly-retired) zero stores

    // ---- ones + histogram (ordered after zeros by the barrier) ----
    if (tid < 64) {
        const int bk = s_bk[tid];
        atomicAdd((unsigned int*)ws + 1024 + bk, 1u);
        encrow0[(size_t)tid * 1024 + bk] = 1.0f;
    }

    // ---- quant + loss from LDS bf16 winner row (no global loads) ----
    {
        const int p  = wv * 16 + n16;
        const int bk = s_bk[p];
        const int ch = (bk >> 4) * 2;
        const int fl = quad * 16 + (bk & 15);
        const S8 w0 = {frag_lds[ch * 64 + fl]};
        const S8 w1 = {frag_lds[(ch + 1) * 64 + fl]};
        float* qbase = out + Q_OFF + (size_t)b * CHW + hw0 + p;
        float lsum = 0.f;
        #pragma unroll
        for (int j = 0; j < 8; ++j) {
            const int d = quad * 8 + j;
            const float q0 = bf2f(w0.u[j]);
            const float q1 = bf2f(w1.u[j]);
            const float d0 = q0 - qx[j];
            const float d1 = q1 - qx[j + 8];
            lsum = fmaf(d0, d0, lsum);
            lsum = fmaf(d1, d1, lsum);
            qbase[d * HW]        = qx[j] + d0;       // straight-through arithmetic
            qbase[(d + 32) * HW] = qx[j + 8] + d1;
        }
        #pragma unroll
        for (int off = 1; off < 64; off <<= 1) lsum += __shfl_xor(lsum, off, 64);
        if (lane == 0) atomicAdd(ws + 2048, lsum);
    }
}

__global__ __launch_bounds__(256) void vq_final(const float* __restrict__ ws,
                                                float* __restrict__ out) {
    __shared__ float red[256];
    const int tid = threadIdx.x;
    const unsigned int* hist = (const unsigned int*)ws + 1024;
    float local = 0.f;
    #pragma unroll
    for (int j = 0; j < 4; ++j) {
        const unsigned int cnt = hist[tid + j * 256];
        const float pr = (float)cnt * (1.0f / 65536.0f);
        local += pr * logf(pr + 1e-10f);
    }
    red[tid] = local;
    __syncthreads();
    for (int off = 128; off > 0; off >>= 1) {
        if (tid < off) red[tid] += red[tid + off];
        __syncthreads();
    }
    if (tid == 0) {
        out[PERP_OFF] = expf(-red[0]);
        out[0] = 1.25f * ws[2048] * (1.0f / 4194304.0f);
    }
}

extern "C" void kernel_launch(void* const* d_in, const int* in_sizes, int n_in,
                              void* d_out, int out_size, void* d_ws, size_t ws_size,
                              hipStream_t stream) {
    const float* in = (const float*)d_in[0];   // (16,64,64,64) fp32 NCHW
    const float* W  = (const float*)d_in[1];   // (1024,64) fp32
    float* out = (float*)d_out;                // [loss | quant(4194304) | perp | enc(67108864)]
    float* ws  = (float*)d_ws;

    vq_prep<<<32, 256, 0, stream>>>(W, ws);
    vq_main<<<NPTS / 64, 256, 0, stream>>>(in, W, out, ws);
    vq_final<<<1, 256, 0, stream>>>(ws, out);
}